// Round 11
// baseline (584.308 us; speedup 1.0000x reference)
//
#include <hip/hip_runtime.h>

typedef _Float16 half8 __attribute__((ext_vector_type(8)));
typedef float floatx4 __attribute__((ext_vector_type(4)));

#define Bsz 512
#define Tsz 168
#define Fsz 16
#define Hsz 256
#define KTILES 9      // K = 288 = 9 * 32  (256 h + 16 x + 16 zero pad)
#define LDS_K 296     // padded LDS row stride in halves

// workspace layout (bytes, all 16B aligned)
#define WSW_OFF   0          // swizzled [w_hh|w_ih|0] f16 frags: 64nt*9kt*64lane*16B = 589824
#define BIAS_OFF  589824     // reordered (b_ih+b_hh) fp32: 1024*4 = 4096
#define FC1_OFF   593920     // fc1 frags: 8nt*8kt*64*16B = 65536
#define FC2_OFF   659456     // fc2 frags: 4nt*4kt*64*16B = 16384
#define HH_OFF    675840     // h history f16 [B][T][H]: 512*168*256*2 = 44040192
#define XBUF_OFF  (HH_OFF + 44040192)   // tagged exchange ring: 32bb*2*16m*128slot*8B = 1 MB

// ---------------- fused prep: all weight swizzles + bias in ONE launch -----
// (was 4 kernels ~19us; launch overhead dominated)
// whh swizzle: nt -> J=nt>>2, g=nt&3 (torch i,f,g,o); B-frag lane=n_in+16*kg
// holds B[k=kt*32+kg*8+e][n].
__global__ __launch_bounds__(256) void k_prep(
    const float* __restrict__ w_hh, const float* __restrict__ w_ih,
    const float* __restrict__ b_ih, const float* __restrict__ b_hh,
    const float* __restrict__ fc1_w, const float* __restrict__ fc2_w,
    _Float16* __restrict__ wsw, float* __restrict__ bias,
    _Float16* __restrict__ w1f, _Float16* __restrict__ w2f) {
    const int b = blockIdx.x, tid = threadIdx.x;
    const int lane = tid & 63, sub = tid >> 6;
    if (b < 144) {                         // w_hh|w_ih swizzle: 576 tiles
        int tile = b * 4 + sub;            // nt*9 + kt
        int nt = tile / KTILES, kt = tile - nt * KTILES;
        int n_in = lane & 15, kg = lane >> 4;
        int J = nt >> 2, g = nt & 3;
        int n_orig = g * 256 + J * 16 + n_in;
        half8 v;
#pragma unroll
        for (int e = 0; e < 8; ++e) {
            int k = kt * 32 + kg * 8 + e;
            float f;
            if (k < 256)      f = w_hh[n_orig * 256 + k];
            else if (k < 272) f = w_ih[n_orig * 16 + (k - 256)];
            else              f = 0.0f;
            v[e] = (_Float16)f;
        }
        ((half8*)wsw)[tile * 64 + lane] = v;
    } else if (b < 148) {                  // bias reorder: 1024
        int id = (b - 144) * 256 + tid;
        int nt = id >> 4, n = id & 15;
        int J = nt >> 2, g = nt & 3;
        int n_orig = g * 256 + J * 16 + n;
        bias[id] = b_ih[n_orig] + b_hh[n_orig];
    } else if (b < 164) {                  // fc1 swizzle: 64 tiles (8nt x 8kt)
        int tile = (b - 148) * 4 + sub;
        int nt = tile >> 3, kt = tile & 7;
        int n_in = lane & 15, kg = lane >> 4;
        half8 v;
#pragma unroll
        for (int e = 0; e < 8; ++e)
            v[e] = (_Float16)fc1_w[(nt * 16 + n_in) * 256 + kt * 32 + kg * 8 + e];
        ((half8*)w1f)[tile * 64 + lane] = v;
    } else {                               // fc2 swizzle: 16 tiles (4nt x 4kt)
        int tile = (b - 164) * 4 + sub;
        int nt = tile >> 2, kt = tile & 3;
        int n_in = lane & 15, kg = lane >> 4;
        half8 v;
#pragma unroll
        for (int e = 0; e < 8; ++e)
            v[e] = (_Float16)fc2_w[(nt * 16 + n_in) * 128 + kt * 32 + kg * 8 + e];
        ((half8*)w2f)[tile * 64 + lane] = v;
    }
}

// ---------------- recurrent LSTM v11: in-wave cell, de-gated publish -------
// 128 WGs = 32 bb x 4 ng, 256 threads (4 waves). Wave w owns J-block
// J = ng*4+w (16 j) x ALL 4 gates (36 MFMA from LDS weights) -> cell update
// fully in-wave: NO glds exchange, NO G1 barrier. Each wave packs j-pairs
// via shfl_xor and publishes its tagged atoms right after ITS cell -- the
// cross-WG critical path is no longer gated by the slowest wave's barrier
// (v10: MFMA -> glds -> G1 -> cell -> publish). Exchange protocol/layout
// byte-identical to v10 (tagged-atom 2-deep ring, batched concurrent polls).
__global__ __launch_bounds__(256, 1) void k_lstm11(
    const float* __restrict__ x, const _Float16* __restrict__ wsw,
    const float* __restrict__ bias, unsigned* __restrict__ hh32,
    unsigned long long* __restrict__ xbuf) {
    __shared__ __align__(16) _Float16 wsh[16 * 8 * 512];  // 16 nt x 8 kt = 128 KB
    __shared__ __align__(16) _Float16 h_lds[16][LDS_K];   // h | x | pad

    const int tid = threadIdx.x;
    const int wave = tid >> 6, lane = tid & 63;
    const int n_in = lane & 15, quad = lane >> 4;
    const int bb = blockIdx.x >> 2, ng = blockIdx.x & 3;
    const int b0 = bb * 16;
    const int jbase = ng * 64 + wave * 16;   // wave's 16 columns (global j)

    // ---- one-time: stage 16 nt x kt=0..7 weight tiles into LDS ----
    {
        const float4* srcw = (const float4*)wsw;
        float4* dstw = (float4*)wsh;
#pragma unroll
        for (int it = 0; it < 32; ++it) {
            int i = it * 256 + tid;          // i = nt_l*512 + kt*64 + f4
            dstw[i] = srcw[(size_t)(ng * 16 + (i >> 9)) * 576 + (i & 511)];
        }
    }
    // biases + loop-invariant kt=8 B-frags (x|zero cols): 4 gates of J-block
    float bs[4];
    half8 wx[4];
#pragma unroll
    for (int g = 0; g < 4; ++g) {
        const int nt = ng * 16 + wave * 4 + g;
        bs[g] = bias[nt * 16 + n_in];
        wx[g] = ((const half8*)wsw)[((size_t)nt * KTILES + 8) * 64 + lane];
    }

    // zero h0 + x + pad, stage x_0
    for (int i = tid; i < 16 * LDS_K; i += 256)
        ((_Float16*)h_lds)[i] = (_Float16)0.0f;
    __syncthreads();
    {
        int m = tid >> 4, f = tid & 15;
        h_lds[m][Hsz + f] = (_Float16)x[((b0 + m) * Tsz + 0) * Fsz + f];
    }
    __syncthreads();

    const int gm = tid >> 4, gp2 = tid & 15;   // gather/x ownership: m, col-pair
    const int jp_local = wave * 8 + (n_in >> 1);  // publish j-pair slot 0..31
    float c_st[4] = {0.f, 0.f, 0.f, 0.f};     // lane owns m=quad*4+r, j=jbase+n_in

    for (int t = 0; t < Tsz; ++t) {
        // ---- A-frags from LDS ----
        half8 afr[KTILES];
#pragma unroll
        for (int kt = 0; kt < KTILES; ++kt)
            afr[kt] = *(const half8*)&h_lds[n_in][kt * 32 + quad * 8];
        __syncthreads();   // G0: afr reads done -> h_lds writable this step

        // ---- MFMA: 4 gates x (8 kt from LDS + kt=8 from regs) ----
        floatx4 acc[4];
#pragma unroll
        for (int g = 0; g < 4; ++g) acc[g] = (floatx4){0.f, 0.f, 0.f, 0.f};
#pragma unroll
        for (int g = 0; g < 4; ++g) {
            const int nt_l = wave * 4 + g;
#pragma unroll
            for (int kt = 0; kt < 8; ++kt) {
                half8 bfr = *(const half8*)&wsh[((nt_l << 3) + kt) * 512 + lane * 8];
                acc[g] = __builtin_amdgcn_mfma_f32_16x16x32_f16(afr[kt], bfr, acc[g], 0, 0, 0);
            }
            acc[g] = __builtin_amdgcn_mfma_f32_16x16x32_f16(afr[8], wx[g], acc[g], 0, 0, 0);
        }

        // ---- in-wave cell update: lane owns 4 (m, j) pairs ----
        _Float16 hv[4];
#pragma unroll
        for (int r = 0; r < 4; ++r) {
            float ig = acc[0][r] + bs[0];
            float fg = acc[1][r] + bs[1];
            float gg = acc[2][r] + bs[2];
            float og = acc[3][r] + bs[3];
            float si = 1.0f / (1.0f + __expf(-ig));
            float sf = 1.0f / (1.0f + __expf(-fg));
            float tg = 1.0f - 2.0f / (__expf(2.0f * gg) + 1.0f);
            float so = 1.0f / (1.0f + __expf(-og));
            float c = sf * c_st[r] + si * tg;
            c_st[r] = c;
            float th = 1.0f - 2.0f / (__expf(2.0f * c) + 1.0f);
            hv[r] = (_Float16)(so * th);
        }

        // ---- pack j-pairs cross-lane; even lanes publish immediately ----
        unsigned d0 = (unsigned)__builtin_bit_cast(unsigned short, hv[0]) |
                      ((unsigned)__builtin_bit_cast(unsigned short, hv[1]) << 16);
        unsigned d1 = (unsigned)__builtin_bit_cast(unsigned short, hv[2]) |
                      ((unsigned)__builtin_bit_cast(unsigned short, hv[3]) << 16);
        unsigned p0 = (unsigned)__shfl_xor((int)d0, 1);
        unsigned p1 = (unsigned)__shfl_xor((int)d1, 1);
        const size_t rb = (size_t)(bb * 2 + (t & 1)) * 16;   // ring base (rows)
        if (!(n_in & 1)) {
            unsigned aw[4];
            aw[0] = (d0 & 0xFFFFu) | ((p0 & 0xFFFFu) << 16);   // m=quad*4+0
            aw[1] = (d0 >> 16)     | (p0 & 0xFFFF0000u);       // m=quad*4+1
            aw[2] = (d1 & 0xFFFFu) | ((p1 & 0xFFFFu) << 16);   // m=quad*4+2
            aw[3] = (d1 >> 16)     | (p1 & 0xFFFF0000u);       // m=quad*4+3
            if (t + 1 < Tsz) {
#pragma unroll
                for (int r = 0; r < 4; ++r)
                    __hip_atomic_store(
                        &xbuf[(rb + quad * 4 + r) * 128 + ng * 32 + jp_local],
                        ((unsigned long long)aw[r] << 32) | (unsigned)(t + 1),
                        __ATOMIC_RELAXED, __HIP_MEMORY_SCOPE_AGENT);
            }
#pragma unroll
            for (int r = 0; r < 4; ++r)   // history for k_mlp (plain store)
                hh32[((size_t)(b0 + quad * 4 + r) * Tsz + t) * 128 + ng * 32 + jp_local] = aw[r];
        }

        // own-quarter h_{t+1} into LDS (safe: after G0)
#pragma unroll
        for (int r = 0; r < 4; ++r)
            h_lds[quad * 4 + r][jbase + n_in] = hv[r];

        if (t + 1 < Tsz) {
            // x prefetch; ack overlaps polls
            float xr = x[((b0 + gm) * Tsz + (t + 1)) * Fsz + gp2];

            // ---- gather 3 partner quarters: 6 concurrent tagged-atom polls ----
            const unsigned want = (unsigned)(t + 1);
            unsigned long long vv[6];
            unsigned long long* pp[6];
#pragma unroll
            for (int q = 0; q < 3; ++q) {
                int pq = (ng + 1 + q) & 3;
#pragma unroll
                for (int e = 0; e < 2; ++e)
                    pp[q * 2 + e] = &xbuf[(rb + gm) * 128 + pq * 32 + 2 * gp2 + e];
            }
#pragma unroll
            for (int i = 0; i < 6; ++i)
                vv[i] = __hip_atomic_load(pp[i], __ATOMIC_RELAXED,
                                          __HIP_MEMORY_SCOPE_AGENT);
            for (;;) {
                bool miss = false;
#pragma unroll
                for (int i = 0; i < 6; ++i) miss |= ((unsigned)vv[i] != want);
                if (!miss) break;
#pragma unroll
                for (int i = 0; i < 6; ++i)
                    if ((unsigned)vv[i] != want)
                        vv[i] = __hip_atomic_load(pp[i], __ATOMIC_RELAXED,
                                                  __HIP_MEMORY_SCOPE_AGENT);
            }
#pragma unroll
            for (int q = 0; q < 3; ++q) {
                int pq = (ng + 1 + q) & 3;
#pragma unroll
                for (int e = 0; e < 2; ++e)
                    *(unsigned*)&h_lds[gm][pq * 64 + 4 * gp2 + 2 * e] =
                        (unsigned)(vv[q * 2 + e] >> 32);
            }
            h_lds[gm][Hsz + gp2] = (_Float16)xr;
            __syncthreads();   // G4: full h_{t+1} + x_{t+1} staged
        }
    }
}

// ---------------- MLP head v2: LDS-staged weights, 128 tokens/WG -----------
// R10 analysis: old k_mlp re-read 80 KB of fc1/fc2 frags from L2 per wave
// (5376 waves -> ~430 MB L2 restream = the 75us). v2: 672 WGs x 512 thr,
// frags staged once into LDS (80 KB), 8 waves x 16 tokens each.
__global__ __launch_bounds__(512, 1) void k_mlp2(
    const _Float16* __restrict__ hh, const _Float16* __restrict__ w1f,
    const _Float16* __restrict__ w2f, const float* __restrict__ b1,
    const float* __restrict__ b2, const float* __restrict__ w3,
    const float* __restrict__ b3, float* __restrict__ out) {
    __shared__ __align__(16) _Float16 w1sh[64 * 512];   // 64 KB
    __shared__ __align__(16) _Float16 w2sh[16 * 512];   // 16 KB
    __shared__ _Float16 st1[8][16][136];
    __shared__ _Float16 st2[8][16][72];

    const int tid = threadIdx.x;
    const int wave = tid >> 6, lane = tid & 63;
    const int n_in = lane & 15, quad = lane >> 4;
    const int tok0 = blockIdx.x * 128 + wave * 16;

    {   // stage fragment tables (linear copy; layout already frag-ordered)
        float4* d1 = (float4*)w1sh;
        const float4* s1 = (const float4*)w1f;
#pragma unroll
        for (int it = 0; it < 8; ++it) d1[it * 512 + tid] = s1[it * 512 + tid];
        float4* d2 = (float4*)w2sh;
        const float4* s2 = (const float4*)w2f;
#pragma unroll
        for (int it = 0; it < 2; ++it) d2[it * 512 + tid] = s2[it * 512 + tid];
    }
    __syncthreads();

    half8 afr[8];
#pragma unroll
    for (int kt = 0; kt < 8; ++kt)
        afr[kt] = *(const half8*)&hh[(size_t)(tok0 + n_in) * 256 + kt * 32 + quad * 8];
#pragma unroll
    for (int nt = 0; nt < 8; ++nt) {
        floatx4 a = (floatx4){0.f, 0.f, 0.f, 0.f};
#pragma unroll
        for (int kt = 0; kt < 8; ++kt) {
            half8 bfr = *(const half8*)&w1sh[(nt * 8 + kt) * 512 + lane * 8];
            a = __builtin_amdgcn_mfma_f32_16x16x32_f16(afr[kt], bfr, a, 0, 0, 0);
        }
        float bb = b1[nt * 16 + n_in];
#pragma unroll
        for (int r = 0; r < 4; ++r) {
            float v = a[r] + bb;
            st1[wave][quad * 4 + r][nt * 16 + n_in] = (_Float16)(v > 0.f ? v : 0.f);
        }
    }
    __syncthreads();

    half8 a2[4];
#pragma unroll
    for (int kt = 0; kt < 4; ++kt)
        a2[kt] = *(const half8*)&st1[wave][n_in][kt * 32 + quad * 8];
#pragma unroll
    for (int nt = 0; nt < 4; ++nt) {
        floatx4 a = (floatx4){0.f, 0.f, 0.f, 0.f};
#pragma unroll
        for (int kt = 0; kt < 4; ++kt) {
            half8 bfr = *(const half8*)&w2sh[(nt * 4 + kt) * 512 + lane * 8];
            a = __builtin_amdgcn_mfma_f32_16x16x32_f16(a2[kt], bfr, a, 0, 0, 0);
        }
        float bb = b2[nt * 16 + n_in];
#pragma unroll
        for (int r = 0; r < 4; ++r) {
            float v = a[r] + bb;
            st2[wave][quad * 4 + r][nt * 16 + n_in] = (_Float16)(v > 0.f ? v : 0.f);
        }
    }
    __syncthreads();

    float p = 0.0f;
#pragma unroll
    for (int e = 0; e < 16; ++e)
        p += (float)st2[wave][n_in][quad * 16 + e] * w3[quad * 16 + e];
    p += __shfl_down(p, 32);
    p += __shfl_down(p, 16);
    if (quad == 0) out[tok0 + n_in] = p + b3[0];
}

extern "C" void kernel_launch(void* const* d_in, const int* in_sizes, int n_in,
                              void* d_out, int out_size, void* d_ws, size_t ws_size,
                              hipStream_t stream) {
    const float* x     = (const float*)d_in[0];
    const float* w_ih  = (const float*)d_in[1];
    const float* w_hh  = (const float*)d_in[2];
    const float* b_ih  = (const float*)d_in[3];
    const float* b_hh  = (const float*)d_in[4];
    const float* fc1_w = (const float*)d_in[5];
    const float* fc1_b = (const float*)d_in[6];
    const float* fc2_w = (const float*)d_in[7];
    const float* fc2_b = (const float*)d_in[8];
    const float* fc3_w = (const float*)d_in[9];
    const float* fc3_b = (const float*)d_in[10];

    char* ws = (char*)d_ws;
    _Float16* wsw  = (_Float16*)(ws + WSW_OFF);
    float*    bias = (float*)(ws + BIAS_OFF);
    _Float16* w1f  = (_Float16*)(ws + FC1_OFF);
    _Float16* w2f  = (_Float16*)(ws + FC2_OFF);
    _Float16* hhist= (_Float16*)(ws + HH_OFF);
    unsigned long long* xbuf = (unsigned long long*)(ws + XBUF_OFF);

    k_prep<<<168, 256, 0, stream>>>(w_hh, w_ih, b_ih, b_hh, fc1_w, fc2_w,
                                    wsw, bias, w1f, w2f);
    k_lstm11<<<128, 256, 0, stream>>>(x, wsw, bias, (unsigned*)hhist, xbuf);
    k_mlp2<<<672, 512, 0, stream>>>(hhist, w1f, w2f, fc1_b, fc2_b,
                                    fc3_w, fc3_b, (float*)d_out);
}

// Round 12
// 467.799 us; speedup vs baseline: 1.2491x; 1.2491x over previous
//
#include <hip/hip_runtime.h>

typedef _Float16 half8 __attribute__((ext_vector_type(8)));
typedef float floatx4 __attribute__((ext_vector_type(4)));

#define Bsz 512
#define Tsz 168
#define Fsz 16
#define Hsz 256
#define KTILES 9      // K = 288 = 9 * 32  (256 h + 16 x + 16 zero pad)
#define LDS_K 296     // padded LDS row stride in halves

// workspace layout (bytes, all 16B aligned)
#define WSW_OFF   0          // swizzled [w_hh|w_ih|0] f16 frags: 64nt*9kt*64lane*16B = 589824
#define BIAS_OFF  589824     // reordered (b_ih+b_hh) fp32: 1024*4 = 4096
#define FC1_OFF   593920     // fc1 frags: 8nt*8kt*64*16B = 65536
#define FC2_OFF   659456     // fc2 frags: 4nt*4kt*64*16B = 16384
#define HH_OFF    675840     // h history f16 [B][T][H]: 512*168*256*2 = 44040192
#define XBUF_OFF  (HH_OFF + 44040192)   // tagged exchange ring: 32bb*2*16m*128slot*8B = 1 MB

// ---------------- fused prep: all weight swizzles + bias in ONE launch -----
// whh swizzle: nt -> J=nt>>2, g=nt&3 (torch i,f,g,o); B-frag lane=n_in+16*kg
// holds B[k=kt*32+kg*8+e][n].
__global__ __launch_bounds__(256) void k_prep(
    const float* __restrict__ w_hh, const float* __restrict__ w_ih,
    const float* __restrict__ b_ih, const float* __restrict__ b_hh,
    const float* __restrict__ fc1_w, const float* __restrict__ fc2_w,
    _Float16* __restrict__ wsw, float* __restrict__ bias,
    _Float16* __restrict__ w1f, _Float16* __restrict__ w2f) {
    const int b = blockIdx.x, tid = threadIdx.x;
    const int lane = tid & 63, sub = tid >> 6;
    if (b < 144) {                         // w_hh|w_ih swizzle: 576 tiles
        int tile = b * 4 + sub;            // nt*9 + kt
        int nt = tile / KTILES, kt = tile - nt * KTILES;
        int n_in = lane & 15, kg = lane >> 4;
        int J = nt >> 2, g = nt & 3;
        int n_orig = g * 256 + J * 16 + n_in;
        half8 v;
#pragma unroll
        for (int e = 0; e < 8; ++e) {
            int k = kt * 32 + kg * 8 + e;
            float f;
            if (k < 256)      f = w_hh[n_orig * 256 + k];
            else if (k < 272) f = w_ih[n_orig * 16 + (k - 256)];
            else              f = 0.0f;
            v[e] = (_Float16)f;
        }
        ((half8*)wsw)[tile * 64 + lane] = v;
    } else if (b < 148) {                  // bias reorder: 1024
        int id = (b - 144) * 256 + tid;
        int nt = id >> 4, n = id & 15;
        int J = nt >> 2, g = nt & 3;
        int n_orig = g * 256 + J * 16 + n;
        bias[id] = b_ih[n_orig] + b_hh[n_orig];
    } else if (b < 164) {                  // fc1 swizzle: 64 tiles (8nt x 8kt)
        int tile = (b - 148) * 4 + sub;
        int nt = tile >> 3, kt = tile & 7;
        int n_in = lane & 15, kg = lane >> 4;
        half8 v;
#pragma unroll
        for (int e = 0; e < 8; ++e)
            v[e] = (_Float16)fc1_w[(nt * 16 + n_in) * 256 + kt * 32 + kg * 8 + e];
        ((half8*)w1f)[tile * 64 + lane] = v;
    } else {                               // fc2 swizzle: 16 tiles (4nt x 4kt)
        int tile = (b - 164) * 4 + sub;
        int nt = tile >> 2, kt = tile & 3;
        int n_in = lane & 15, kg = lane >> 4;
        half8 v;
#pragma unroll
        for (int e = 0; e < 8; ++e)
            v[e] = (_Float16)fc2_w[(nt * 16 + n_in) * 128 + kt * 32 + kg * 8 + e];
        ((half8*)w2f)[tile * 64 + lane] = v;
    }
}

// ---------------- recurrent LSTM v12: v10 structure + XCD-colocated partners
// EXACT v10 body (known 413us; v11's 4-wave variant regressed to 506 -- at
// 1 wave/SIMD the cell VALU + 36-MFMA chain loses all latency hiding).
// One change: blockIdx = ng*32 + bb, so the 4 exchange partners {bb, 32+bb,
// 64+bb, 96+bb} are all == bb (mod 8) -> SAME XCD under round-robin
// dispatch: shared L2 locality + correlated skew on the degree-4 AND-join.
// (Heuristic only -- protocol correctness does not depend on placement.)
__global__ __launch_bounds__(512, 1) void k_lstm12(
    const float* __restrict__ x, const _Float16* __restrict__ wsw,
    const float* __restrict__ bias, unsigned* __restrict__ hh32,
    unsigned long long* __restrict__ xbuf) {
    __shared__ __align__(16) _Float16 wsh[16 * 8 * 512];  // 16 nt x 8 kt x 1 KB = 128 KB
    __shared__ __align__(16) _Float16 h_lds[16][LDS_K];   // h | x | pad
    __shared__ float glds[4][16][68];                     // [gate][m][j_local], pad 68

    const int tid = threadIdx.x;
    const int wave = tid >> 6, lane = tid & 63;
    const int n_in = lane & 15, quad = lane >> 4;
    const int bb = blockIdx.x & 31, ng = blockIdx.x >> 5;   // XCD-colocated swizzle
    const int b0 = bb * 16;
    const int Jl = wave & 3;               // local J-block 0..3
    const int gp = wave >> 2;              // gate pair: 0 -> (i,f), 1 -> (g,o)

    // ---- one-time: stage this WG's 16 nt x kt=0..7 weight tiles into LDS ----
    {
        const float4* srcw = (const float4*)wsw;
        float4* dstw = (float4*)wsh;
#pragma unroll
        for (int it = 0; it < 16; ++it) {
            int i = it * 512 + tid;        // i = nt_l*512 + kt*64 + f4 (kt 0..7)
            dstw[i] = srcw[(size_t)(ng * 16 + (i >> 9)) * 576 + (i & 511)];
        }
    }
    // biases + loop-invariant kt=8 B-frags (x | zero cols) in registers
    float bs[2];
    half8 wx[2];
#pragma unroll
    for (int gg = 0; gg < 2; ++gg) {
        const int nt = ng * 16 + Jl * 4 + gp * 2 + gg;
        bs[gg] = bias[nt * 16 + n_in];
        wx[gg] = ((const half8*)wsw)[((size_t)nt * KTILES + 8) * 64 + lane];
    }

    // zero h0 + x + pad, stage x_0
    for (int i = tid; i < 16 * LDS_K; i += 512)
        ((_Float16*)h_lds)[i] = (_Float16)0.0f;
    __syncthreads();
    if (tid < 256) {
        int m = tid >> 4, f = tid & 15;
        h_lds[m][Hsz + f] = (_Float16)x[((b0 + m) * Tsz + 0) * Fsz + f];
    }
    __syncthreads();

    // cell/publish/gather ownership: thread -> (m = tid>>5, slot = tid&31)
    const int cm = tid >> 5, cj = tid & 31;
    float c_st[2] = {0.f, 0.f};

    for (int t = 0; t < Tsz; ++t) {
        // ---- A-frags from LDS; B-frags: kt=0..7 from LDS, kt=8 from regs ----
        half8 afr[KTILES];
#pragma unroll
        for (int kt = 0; kt < KTILES; ++kt)
            afr[kt] = *(const half8*)&h_lds[n_in][kt * 32 + quad * 8];

        floatx4 acc[2] = {(floatx4){0.f,0.f,0.f,0.f}, (floatx4){0.f,0.f,0.f,0.f}};
#pragma unroll
        for (int gg = 0; gg < 2; ++gg) {
            const int nt_l = Jl * 4 + gp * 2 + gg;
#pragma unroll
            for (int kt = 0; kt < 8; ++kt) {
                half8 bfr = *(const half8*)&wsh[((nt_l << 3) + kt) * 512 + lane * 8];
                acc[gg] = __builtin_amdgcn_mfma_f32_16x16x32_f16(afr[kt], bfr, acc[gg], 0, 0, 0);
            }
            acc[gg] = __builtin_amdgcn_mfma_f32_16x16x32_f16(afr[8], wx[gg], acc[gg], 0, 0, 0);
        }

        // ---- stage gate pre-activations to LDS ----
#pragma unroll
        for (int gg = 0; gg < 2; ++gg)
#pragma unroll
            for (int r = 0; r < 4; ++r)
                glds[gp * 2 + gg][quad * 4 + r][Jl * 16 + n_in] = acc[gg][r] + bs[gg];
        __syncthreads();   // G1: gates staged; afr reads done -> h_lds writable

        // ---- cell update: thread owns (cm, j_local = 2cj, 2cj+1) ----
        union { _Float16 f[2]; unsigned u; } pk;
#pragma unroll
        for (int e = 0; e < 2; ++e) {
            int jl = 2 * cj + e;
            float ig = glds[0][cm][jl];
            float fg = glds[1][cm][jl];
            float gg_ = glds[2][cm][jl];
            float og = glds[3][cm][jl];
            float si = 1.0f / (1.0f + __expf(-ig));
            float sf = 1.0f / (1.0f + __expf(-fg));
            float tg = 1.0f - 2.0f / (__expf(2.0f * gg_) + 1.0f);
            float so = 1.0f / (1.0f + __expf(-og));
            float c = sf * c_st[e] + si * tg;
            c_st[e] = c;
            float th = 1.0f - 2.0f / (__expf(2.0f * c) + 1.0f);
            pk.f[e] = (_Float16)(so * th);
        }
        // own quarter of h_{t+1} straight into LDS (safe: reads done at G1)
        *(unsigned*)&h_lds[cm][ng * 64 + 2 * cj] = pk.u;
        // history write for k_mlp (plain store; kernel-boundary coherence)
        hh32[((size_t)(b0 + cm) * Tsz + t) * 128 + ng * 32 + cj] = pk.u;

        const size_t rb = ((size_t)((bb * 2 + (t & 1)) * 16));   // ring base (rows)
        if (t + 1 < Tsz) {
            // publish own slot as a single tagged atom {data | t+1}
            unsigned long long pv = ((unsigned long long)pk.u << 32) | (unsigned)(t + 1);
            __hip_atomic_store(&xbuf[(rb + cm) * 128 + ng * 32 + cj], pv,
                               __ATOMIC_RELAXED, __HIP_MEMORY_SCOPE_AGENT);

            // prefetch x_{t+1}; ack overlaps the polls below
            float xr = 0.0f;
            if (tid < 256)
                xr = x[((b0 + (tid >> 4)) * Tsz + (t + 1)) * Fsz + (tid & 15)];

            // ---- gather 3 partner quarters: CONCURRENT tagged-atom polls ----
            const unsigned want = (unsigned)(t + 1);
            unsigned long long* p1 = &xbuf[(rb + cm) * 128 + ((ng + 1) & 3) * 32 + cj];
            unsigned long long* p2 = &xbuf[(rb + cm) * 128 + ((ng + 2) & 3) * 32 + cj];
            unsigned long long* p3 = &xbuf[(rb + cm) * 128 + ((ng + 3) & 3) * 32 + cj];
            unsigned long long v1 = __hip_atomic_load(p1, __ATOMIC_RELAXED,
                                                      __HIP_MEMORY_SCOPE_AGENT);
            unsigned long long v2 = __hip_atomic_load(p2, __ATOMIC_RELAXED,
                                                      __HIP_MEMORY_SCOPE_AGENT);
            unsigned long long v3 = __hip_atomic_load(p3, __ATOMIC_RELAXED,
                                                      __HIP_MEMORY_SCOPE_AGENT);
            while ((unsigned)v1 != want || (unsigned)v2 != want || (unsigned)v3 != want) {
                if ((unsigned)v1 != want)
                    v1 = __hip_atomic_load(p1, __ATOMIC_RELAXED, __HIP_MEMORY_SCOPE_AGENT);
                if ((unsigned)v2 != want)
                    v2 = __hip_atomic_load(p2, __ATOMIC_RELAXED, __HIP_MEMORY_SCOPE_AGENT);
                if ((unsigned)v3 != want)
                    v3 = __hip_atomic_load(p3, __ATOMIC_RELAXED, __HIP_MEMORY_SCOPE_AGENT);
            }
            *(unsigned*)&h_lds[cm][((ng + 1) & 3) * 64 + 2 * cj] = (unsigned)(v1 >> 32);
            *(unsigned*)&h_lds[cm][((ng + 2) & 3) * 64 + 2 * cj] = (unsigned)(v2 >> 32);
            *(unsigned*)&h_lds[cm][((ng + 3) & 3) * 64 + 2 * cj] = (unsigned)(v3 >> 32);
            if (tid < 256)
                h_lds[tid >> 4][Hsz + (tid & 15)] = (_Float16)xr;
            __syncthreads();   // G4: full h_{t+1} + x_{t+1} staged
        }
    }
}

// ---------------- MLP head v3: LDS weights + persistent grid-stride chunks -
// 224 WGs x 512 thr; weights staged ONCE per WG (v11 staged per 128-token
// chunk x 672 WGs = 3x the staging traffic). 672 chunks / 224 WGs = 3 each.
// All st1/st2 accesses are [wave]-private -> chunk loop needs no extra sync.
__global__ __launch_bounds__(512, 1) void k_mlp3(
    const _Float16* __restrict__ hh, const _Float16* __restrict__ w1f,
    const _Float16* __restrict__ w2f, const float* __restrict__ b1,
    const float* __restrict__ b2, const float* __restrict__ w3,
    const float* __restrict__ b3, float* __restrict__ out) {
    __shared__ __align__(16) _Float16 w1sh[64 * 512];   // 64 KB
    __shared__ __align__(16) _Float16 w2sh[16 * 512];   // 16 KB
    __shared__ _Float16 st1[8][16][136];
    __shared__ _Float16 st2[8][16][72];

    const int tid = threadIdx.x;
    const int wave = tid >> 6, lane = tid & 63;
    const int n_in = lane & 15, quad = lane >> 4;

    {   // stage fragment tables once (layout already frag-ordered)
        float4* d1 = (float4*)w1sh;
        const float4* s1 = (const float4*)w1f;
#pragma unroll
        for (int it = 0; it < 8; ++it) d1[it * 512 + tid] = s1[it * 512 + tid];
        float4* d2 = (float4*)w2sh;
        const float4* s2 = (const float4*)w2f;
#pragma unroll
        for (int it = 0; it < 2; ++it) d2[it * 512 + tid] = s2[it * 512 + tid];
    }
    __syncthreads();

    for (int chunk = blockIdx.x; chunk < (Bsz * Tsz) / 128; chunk += gridDim.x) {
        const int tok0 = chunk * 128 + wave * 16;

        half8 afr[8];
#pragma unroll
        for (int kt = 0; kt < 8; ++kt)
            afr[kt] = *(const half8*)&hh[(size_t)(tok0 + n_in) * 256 + kt * 32 + quad * 8];
#pragma unroll
        for (int nt = 0; nt < 8; ++nt) {
            floatx4 a = (floatx4){0.f, 0.f, 0.f, 0.f};
#pragma unroll
            for (int kt = 0; kt < 8; ++kt) {
                half8 bfr = *(const half8*)&w1sh[(nt * 8 + kt) * 512 + lane * 8];
                a = __builtin_amdgcn_mfma_f32_16x16x32_f16(afr[kt], bfr, a, 0, 0, 0);
            }
            float bb = b1[nt * 16 + n_in];
#pragma unroll
            for (int r = 0; r < 4; ++r) {
                float v = a[r] + bb;
                st1[wave][quad * 4 + r][nt * 16 + n_in] = (_Float16)(v > 0.f ? v : 0.f);
            }
        }

        half8 a2[4];
#pragma unroll
        for (int kt = 0; kt < 4; ++kt)
            a2[kt] = *(const half8*)&st1[wave][n_in][kt * 32 + quad * 8];
#pragma unroll
        for (int nt = 0; nt < 4; ++nt) {
            floatx4 a = (floatx4){0.f, 0.f, 0.f, 0.f};
#pragma unroll
            for (int kt = 0; kt < 4; ++kt) {
                half8 bfr = *(const half8*)&w2sh[(nt * 4 + kt) * 512 + lane * 8];
                a = __builtin_amdgcn_mfma_f32_16x16x32_f16(a2[kt], bfr, a, 0, 0, 0);
            }
            float bb = b2[nt * 16 + n_in];
#pragma unroll
            for (int r = 0; r < 4; ++r) {
                float v = a[r] + bb;
                st2[wave][quad * 4 + r][nt * 16 + n_in] = (_Float16)(v > 0.f ? v : 0.f);
            }
        }

        float p = 0.0f;
#pragma unroll
        for (int e = 0; e < 16; ++e)
            p += (float)st2[wave][n_in][quad * 16 + e] * w3[quad * 16 + e];
        p += __shfl_down(p, 32);
        p += __shfl_down(p, 16);
        if (quad == 0) out[tok0 + n_in] = p + b3[0];
    }
}

extern "C" void kernel_launch(void* const* d_in, const int* in_sizes, int n_in,
                              void* d_out, int out_size, void* d_ws, size_t ws_size,
                              hipStream_t stream) {
    const float* x     = (const float*)d_in[0];
    const float* w_ih  = (const float*)d_in[1];
    const float* w_hh  = (const float*)d_in[2];
    const float* b_ih  = (const float*)d_in[3];
    const float* b_hh  = (const float*)d_in[4];
    const float* fc1_w = (const float*)d_in[5];
    const float* fc1_b = (const float*)d_in[6];
    const float* fc2_w = (const float*)d_in[7];
    const float* fc2_b = (const float*)d_in[8];
    const float* fc3_w = (const float*)d_in[9];
    const float* fc3_b = (const float*)d_in[10];

    char* ws = (char*)d_ws;
    _Float16* wsw  = (_Float16*)(ws + WSW_OFF);
    float*    bias = (float*)(ws + BIAS_OFF);
    _Float16* w1f  = (_Float16*)(ws + FC1_OFF);
    _Float16* w2f  = (_Float16*)(ws + FC2_OFF);
    _Float16* hhist= (_Float16*)(ws + HH_OFF);
    unsigned long long* xbuf = (unsigned long long*)(ws + XBUF_OFF);

    k_prep<<<168, 256, 0, stream>>>(w_hh, w_ih, b_ih, b_hh, fc1_w, fc2_w,
                                    wsw, bias, w1f, w2f);
    k_lstm12<<<128, 512, 0, stream>>>(x, wsw, bias, (unsigned*)hhist, xbuf);
    k_mlp3<<<224, 512, 0, stream>>>(hhist, w1f, w2f, fc1_b, fc2_b,
                                    fc3_w, fc3_b, (float*)d_out);
}

// Round 13
// 459.931 us; speedup vs baseline: 1.2704x; 1.0171x over previous
//
#include <hip/hip_runtime.h>

typedef _Float16 half8 __attribute__((ext_vector_type(8)));
typedef float floatx4 __attribute__((ext_vector_type(4)));
typedef unsigned uint4v __attribute__((ext_vector_type(4)));

#define Bsz 512
#define Tsz 168
#define Fsz 16
#define Hsz 256
#define KTILES 9      // K = 288 = 9 * 32  (256 h + 16 x + 16 zero pad)
#define LDS_K 296     // padded LDS row stride in halves

// workspace layout (bytes, all 16B aligned)
#define WSW_OFF   0          // swizzled [w_hh|w_ih|0] f16 frags: 64nt*9kt*64lane*16B = 589824
#define BIAS_OFF  589824     // reordered (b_ih+b_hh) fp32: 1024*4 = 4096
#define FC1_OFF   593920     // fc1 frags: 8nt*8kt*64*16B = 65536
#define FC2_OFF   659456     // fc2 frags: 4nt*4kt*64*16B = 16384
#define HH_OFF    675840     // h history f16 [B][T][H]: 512*168*256*2 = 44040192
#define XBUF_OFF  (HH_OFF + 44040192)   // tagged exchange ring: 32bb*2*16m*128slot*8B = 1 MB

// ---------------- fused prep: all weight swizzles + bias in ONE launch -----
__global__ __launch_bounds__(256) void k_prep(
    const float* __restrict__ w_hh, const float* __restrict__ w_ih,
    const float* __restrict__ b_ih, const float* __restrict__ b_hh,
    const float* __restrict__ fc1_w, const float* __restrict__ fc2_w,
    _Float16* __restrict__ wsw, float* __restrict__ bias,
    _Float16* __restrict__ w1f, _Float16* __restrict__ w2f) {
    const int b = blockIdx.x, tid = threadIdx.x;
    const int lane = tid & 63, sub = tid >> 6;
    if (b < 144) {                         // w_hh|w_ih swizzle: 576 tiles
        int tile = b * 4 + sub;            // nt*9 + kt
        int nt = tile / KTILES, kt = tile - nt * KTILES;
        int n_in = lane & 15, kg = lane >> 4;
        int J = nt >> 2, g = nt & 3;
        int n_orig = g * 256 + J * 16 + n_in;
        half8 v;
#pragma unroll
        for (int e = 0; e < 8; ++e) {
            int k = kt * 32 + kg * 8 + e;
            float f;
            if (k < 256)      f = w_hh[n_orig * 256 + k];
            else if (k < 272) f = w_ih[n_orig * 16 + (k - 256)];
            else              f = 0.0f;
            v[e] = (_Float16)f;
        }
        ((half8*)wsw)[tile * 64 + lane] = v;
    } else if (b < 148) {                  // bias reorder: 1024
        int id = (b - 144) * 256 + tid;
        int nt = id >> 4, n = id & 15;
        int J = nt >> 2, g = nt & 3;
        int n_orig = g * 256 + J * 16 + n;
        bias[id] = b_ih[n_orig] + b_hh[n_orig];
    } else if (b < 164) {                  // fc1 swizzle: 64 tiles (8nt x 8kt)
        int tile = (b - 148) * 4 + sub;
        int nt = tile >> 3, kt = tile & 7;
        int n_in = lane & 15, kg = lane >> 4;
        half8 v;
#pragma unroll
        for (int e = 0; e < 8; ++e)
            v[e] = (_Float16)fc1_w[(nt * 16 + n_in) * 256 + kt * 32 + kg * 8 + e];
        ((half8*)w1f)[tile * 64 + lane] = v;
    } else {                               // fc2 swizzle: 16 tiles (4nt x 4kt)
        int tile = (b - 164) * 4 + sub;
        int nt = tile >> 2, kt = tile & 3;
        int n_in = lane & 15, kg = lane >> 4;
        half8 v;
#pragma unroll
        for (int e = 0; e < 8; ++e)
            v[e] = (_Float16)fc2_w[(nt * 16 + n_in) * 128 + kt * 32 + kg * 8 + e];
        ((half8*)w2f)[tile * 64 + lane] = v;
    }
}

// ---------------- recurrent LSTM v13: v12 + non-temporal hh stream ---------
// R12 counters: FETCH 57 MB, of which ~34 MB ~= the exchange volume itself
// -> hh's 44 MB write-allocate stream evicts the 1 MB xbuf ring from the
// XCD L2, so poll rounds pay ~900cyc MALL/HBM RT instead of ~300cyc L2.
// v13: hh history writes are NON-TEMPORAL (no L2 allocate) so xbuf stays
// L2-resident. Body otherwise byte-identical to v12 (XCD-colocated partners,
// tagged-atom ring, batched concurrent polls).
__global__ __launch_bounds__(512, 1) void k_lstm13(
    const float* __restrict__ x, const _Float16* __restrict__ wsw,
    const float* __restrict__ bias, unsigned* __restrict__ hh32,
    unsigned long long* __restrict__ xbuf) {
    __shared__ __align__(16) _Float16 wsh[16 * 8 * 512];  // 16 nt x 8 kt x 1 KB = 128 KB
    __shared__ __align__(16) _Float16 h_lds[16][LDS_K];   // h | x | pad
    __shared__ float glds[4][16][68];                     // [gate][m][j_local], pad 68

    const int tid = threadIdx.x;
    const int wave = tid >> 6, lane = tid & 63;
    const int n_in = lane & 15, quad = lane >> 4;
    const int bb = blockIdx.x & 31, ng = blockIdx.x >> 5;   // XCD-colocated swizzle
    const int b0 = bb * 16;
    const int Jl = wave & 3;               // local J-block 0..3
    const int gp = wave >> 2;              // gate pair: 0 -> (i,f), 1 -> (g,o)

    // ---- one-time: stage this WG's 16 nt x kt=0..7 weight tiles into LDS ----
    {
        const float4* srcw = (const float4*)wsw;
        float4* dstw = (float4*)wsh;
#pragma unroll
        for (int it = 0; it < 16; ++it) {
            int i = it * 512 + tid;        // i = nt_l*512 + kt*64 + f4 (kt 0..7)
            dstw[i] = srcw[(size_t)(ng * 16 + (i >> 9)) * 576 + (i & 511)];
        }
    }
    // biases + loop-invariant kt=8 B-frags (x | zero cols) in registers
    float bs[2];
    half8 wx[2];
#pragma unroll
    for (int gg = 0; gg < 2; ++gg) {
        const int nt = ng * 16 + Jl * 4 + gp * 2 + gg;
        bs[gg] = bias[nt * 16 + n_in];
        wx[gg] = ((const half8*)wsw)[((size_t)nt * KTILES + 8) * 64 + lane];
    }

    // zero h0 + x + pad, stage x_0
    for (int i = tid; i < 16 * LDS_K; i += 512)
        ((_Float16*)h_lds)[i] = (_Float16)0.0f;
    __syncthreads();
    if (tid < 256) {
        int m = tid >> 4, f = tid & 15;
        h_lds[m][Hsz + f] = (_Float16)x[((b0 + m) * Tsz + 0) * Fsz + f];
    }
    __syncthreads();

    // cell/publish/gather ownership: thread -> (m = tid>>5, slot = tid&31)
    const int cm = tid >> 5, cj = tid & 31;
    float c_st[2] = {0.f, 0.f};

    for (int t = 0; t < Tsz; ++t) {
        // ---- A-frags from LDS; B-frags: kt=0..7 from LDS, kt=8 from regs ----
        half8 afr[KTILES];
#pragma unroll
        for (int kt = 0; kt < KTILES; ++kt)
            afr[kt] = *(const half8*)&h_lds[n_in][kt * 32 + quad * 8];

        floatx4 acc[2] = {(floatx4){0.f,0.f,0.f,0.f}, (floatx4){0.f,0.f,0.f,0.f}};
#pragma unroll
        for (int gg = 0; gg < 2; ++gg) {
            const int nt_l = Jl * 4 + gp * 2 + gg;
#pragma unroll
            for (int kt = 0; kt < 8; ++kt) {
                half8 bfr = *(const half8*)&wsh[((nt_l << 3) + kt) * 512 + lane * 8];
                acc[gg] = __builtin_amdgcn_mfma_f32_16x16x32_f16(afr[kt], bfr, acc[gg], 0, 0, 0);
            }
            acc[gg] = __builtin_amdgcn_mfma_f32_16x16x32_f16(afr[8], wx[gg], acc[gg], 0, 0, 0);
        }

        // ---- stage gate pre-activations to LDS ----
#pragma unroll
        for (int gg = 0; gg < 2; ++gg)
#pragma unroll
            for (int r = 0; r < 4; ++r)
                glds[gp * 2 + gg][quad * 4 + r][Jl * 16 + n_in] = acc[gg][r] + bs[gg];
        __syncthreads();   // G1: gates staged; afr reads done -> h_lds writable

        // ---- cell update: thread owns (cm, j_local = 2cj, 2cj+1) ----
        union { _Float16 f[2]; unsigned u; } pk;
#pragma unroll
        for (int e = 0; e < 2; ++e) {
            int jl = 2 * cj + e;
            float ig = glds[0][cm][jl];
            float fg = glds[1][cm][jl];
            float gg_ = glds[2][cm][jl];
            float og = glds[3][cm][jl];
            float si = 1.0f / (1.0f + __expf(-ig));
            float sf = 1.0f / (1.0f + __expf(-fg));
            float tg = 1.0f - 2.0f / (__expf(2.0f * gg_) + 1.0f);
            float so = 1.0f / (1.0f + __expf(-og));
            float c = sf * c_st[e] + si * tg;
            c_st[e] = c;
            float th = 1.0f - 2.0f / (__expf(2.0f * c) + 1.0f);
            pk.f[e] = (_Float16)(so * th);
        }
        // own quarter of h_{t+1} straight into LDS (safe: reads done at G1)
        *(unsigned*)&h_lds[cm][ng * 64 + 2 * cj] = pk.u;

        const size_t rb = ((size_t)((bb * 2 + (t & 1)) * 16));   // ring base (rows)
        if (t + 1 < Tsz) {
            // publish own slot as a single tagged atom {data | t+1} (L2-resident)
            unsigned long long pv = ((unsigned long long)pk.u << 32) | (unsigned)(t + 1);
            __hip_atomic_store(&xbuf[(rb + cm) * 128 + ng * 32 + cj], pv,
                               __ATOMIC_RELAXED, __HIP_MEMORY_SCOPE_AGENT);
        }
        // history write for k_mlp: NON-TEMPORAL -> no L2 allocate, xbuf survives
        __builtin_nontemporal_store(
            pk.u, &hh32[((size_t)(b0 + cm) * Tsz + t) * 128 + ng * 32 + cj]);

        if (t + 1 < Tsz) {
            // prefetch x_{t+1}; ack overlaps the polls below
            float xr = 0.0f;
            if (tid < 256)
                xr = x[((b0 + (tid >> 4)) * Tsz + (t + 1)) * Fsz + (tid & 15)];

            // ---- gather 3 partner quarters: CONCURRENT tagged-atom polls ----
            const unsigned want = (unsigned)(t + 1);
            unsigned long long* p1 = &xbuf[(rb + cm) * 128 + ((ng + 1) & 3) * 32 + cj];
            unsigned long long* p2 = &xbuf[(rb + cm) * 128 + ((ng + 2) & 3) * 32 + cj];
            unsigned long long* p3 = &xbuf[(rb + cm) * 128 + ((ng + 3) & 3) * 32 + cj];
            unsigned long long v1 = __hip_atomic_load(p1, __ATOMIC_RELAXED,
                                                      __HIP_MEMORY_SCOPE_AGENT);
            unsigned long long v2 = __hip_atomic_load(p2, __ATOMIC_RELAXED,
                                                      __HIP_MEMORY_SCOPE_AGENT);
            unsigned long long v3 = __hip_atomic_load(p3, __ATOMIC_RELAXED,
                                                      __HIP_MEMORY_SCOPE_AGENT);
            while ((unsigned)v1 != want || (unsigned)v2 != want || (unsigned)v3 != want) {
                if ((unsigned)v1 != want)
                    v1 = __hip_atomic_load(p1, __ATOMIC_RELAXED, __HIP_MEMORY_SCOPE_AGENT);
                if ((unsigned)v2 != want)
                    v2 = __hip_atomic_load(p2, __ATOMIC_RELAXED, __HIP_MEMORY_SCOPE_AGENT);
                if ((unsigned)v3 != want)
                    v3 = __hip_atomic_load(p3, __ATOMIC_RELAXED, __HIP_MEMORY_SCOPE_AGENT);
            }
            *(unsigned*)&h_lds[cm][((ng + 1) & 3) * 64 + 2 * cj] = (unsigned)(v1 >> 32);
            *(unsigned*)&h_lds[cm][((ng + 2) & 3) * 64 + 2 * cj] = (unsigned)(v2 >> 32);
            *(unsigned*)&h_lds[cm][((ng + 3) & 3) * 64 + 2 * cj] = (unsigned)(v3 >> 32);
            if (tid < 256)
                h_lds[tid >> 4][Hsz + (tid & 15)] = (_Float16)xr;
            __syncthreads();   // G4: full h_{t+1} + x_{t+1} staged
        }
    }
}

// ---------------- MLP head v4: LDS weights + NT hh reads -------------------
// 224 persistent WGs x 512 thr; weights staged once; hh streamed with
// non-temporal loads (read exactly once -> keep L2 for weight frags).
__global__ __launch_bounds__(512, 1) void k_mlp4(
    const _Float16* __restrict__ hh, const _Float16* __restrict__ w1f,
    const _Float16* __restrict__ w2f, const float* __restrict__ b1,
    const float* __restrict__ b2, const float* __restrict__ w3,
    const float* __restrict__ b3, float* __restrict__ out) {
    __shared__ __align__(16) _Float16 w1sh[64 * 512];   // 64 KB
    __shared__ __align__(16) _Float16 w2sh[16 * 512];   // 16 KB
    __shared__ _Float16 st1[8][16][136];
    __shared__ _Float16 st2[8][16][72];

    const int tid = threadIdx.x;
    const int wave = tid >> 6, lane = tid & 63;
    const int n_in = lane & 15, quad = lane >> 4;

    {   // stage fragment tables once (layout already frag-ordered)
        float4* d1 = (float4*)w1sh;
        const float4* s1 = (const float4*)w1f;
#pragma unroll
        for (int it = 0; it < 8; ++it) d1[it * 512 + tid] = s1[it * 512 + tid];
        float4* d2 = (float4*)w2sh;
        const float4* s2 = (const float4*)w2f;
#pragma unroll
        for (int it = 0; it < 2; ++it) d2[it * 512 + tid] = s2[it * 512 + tid];
    }
    __syncthreads();

    for (int chunk = blockIdx.x; chunk < (Bsz * Tsz) / 128; chunk += gridDim.x) {
        const int tok0 = chunk * 128 + wave * 16;

        half8 afr[8];
#pragma unroll
        for (int kt = 0; kt < 8; ++kt) {
            uint4v raw = __builtin_nontemporal_load(
                (const uint4v*)&hh[(size_t)(tok0 + n_in) * 256 + kt * 32 + quad * 8]);
            afr[kt] = __builtin_bit_cast(half8, raw);
        }
#pragma unroll
        for (int nt = 0; nt < 8; ++nt) {
            floatx4 a = (floatx4){0.f, 0.f, 0.f, 0.f};
#pragma unroll
            for (int kt = 0; kt < 8; ++kt) {
                half8 bfr = *(const half8*)&w1sh[(nt * 8 + kt) * 512 + lane * 8];
                a = __builtin_amdgcn_mfma_f32_16x16x32_f16(afr[kt], bfr, a, 0, 0, 0);
            }
            float bb = b1[nt * 16 + n_in];
#pragma unroll
            for (int r = 0; r < 4; ++r) {
                float v = a[r] + bb;
                st1[wave][quad * 4 + r][nt * 16 + n_in] = (_Float16)(v > 0.f ? v : 0.f);
            }
        }

        half8 a2[4];
#pragma unroll
        for (int kt = 0; kt < 4; ++kt)
            a2[kt] = *(const half8*)&st1[wave][n_in][kt * 32 + quad * 8];
#pragma unroll
        for (int nt = 0; nt < 4; ++nt) {
            floatx4 a = (floatx4){0.f, 0.f, 0.f, 0.f};
#pragma unroll
            for (int kt = 0; kt < 4; ++kt) {
                half8 bfr = *(const half8*)&w2sh[(nt * 4 + kt) * 512 + lane * 8];
                a = __builtin_amdgcn_mfma_f32_16x16x32_f16(a2[kt], bfr, a, 0, 0, 0);
            }
            float bb = b2[nt * 16 + n_in];
#pragma unroll
            for (int r = 0; r < 4; ++r) {
                float v = a[r] + bb;
                st2[wave][quad * 4 + r][nt * 16 + n_in] = (_Float16)(v > 0.f ? v : 0.f);
            }
        }

        float p = 0.0f;
#pragma unroll
        for (int e = 0; e < 16; ++e)
            p += (float)st2[wave][n_in][quad * 16 + e] * w3[quad * 16 + e];
        p += __shfl_down(p, 32);
        p += __shfl_down(p, 16);
        if (quad == 0) out[tok0 + n_in] = p + b3[0];
    }
}

extern "C" void kernel_launch(void* const* d_in, const int* in_sizes, int n_in,
                              void* d_out, int out_size, void* d_ws, size_t ws_size,
                              hipStream_t stream) {
    const float* x     = (const float*)d_in[0];
    const float* w_ih  = (const float*)d_in[1];
    const float* w_hh  = (const float*)d_in[2];
    const float* b_ih  = (const float*)d_in[3];
    const float* b_hh  = (const float*)d_in[4];
    const float* fc1_w = (const float*)d_in[5];
    const float* fc1_b = (const float*)d_in[6];
    const float* fc2_w = (const float*)d_in[7];
    const float* fc2_b = (const float*)d_in[8];
    const float* fc3_w = (const float*)d_in[9];
    const float* fc3_b = (const float*)d_in[10];

    char* ws = (char*)d_ws;
    _Float16* wsw  = (_Float16*)(ws + WSW_OFF);
    float*    bias = (float*)(ws + BIAS_OFF);
    _Float16* w1f  = (_Float16*)(ws + FC1_OFF);
    _Float16* w2f  = (_Float16*)(ws + FC2_OFF);
    _Float16* hhist= (_Float16*)(ws + HH_OFF);
    unsigned long long* xbuf = (unsigned long long*)(ws + XBUF_OFF);

    k_prep<<<168, 256, 0, stream>>>(w_hh, w_ih, b_ih, b_hh, fc1_w, fc2_w,
                                    wsw, bias, w1f, w2f);
    k_lstm13<<<128, 512, 0, stream>>>(x, wsw, bias, (unsigned*)hhist, xbuf);
    k_mlp4<<<224, 512, 0, stream>>>(hhist, w1f, w2f, fc1_b, fc2_b,
                                    fc3_w, fc3_b, (float*)d_out);
}